// Round 1
// baseline (599.979 us; speedup 1.0000x reference)
//
#include <hip/hip_runtime.h>

// Batched Jacobi diffusion, B=8, 128x128, iters=1000. One 1024-thread block
// per batch. Wave-strip layout: 16 waves x 8 grid rows; lane owns a float2
// column pair. VALU-issue-bound on 8 active CUs (VALUBusy ~83% there).
//
// Round 14: two fixes against the measured ~2x VALU instruction bloat
// (~17 instr/row vs the intended 8, with VGPR_Count=64):
//  1. __launch_bounds__(NT, 4): we launch exactly 1 block/CU, so demand the
//     128-VGPR budget (4 waves/EU). The ~112-reg live set (64 coef + 32
//     state + temps) now fits in arch VGPRs -> no AGPR spill churn
//     (v_accvgpr_read/write on every coefficient use each step).
//  2. Inline-asm v_pk_fma_f32 / v_pk_mul_f32 guarantees VOP3P packing; the
//     cc.yx half-swap is a free op_sel:[0,1] op_sel_hi:[1,0] on src1.
// Target per row: 2 mov + 2 DPP + 1 pk_mul + 3 pk_fma = 8 VALU slots.

#define GH 128
#define GW 128
#define NW 16      // waves per block
#define RPW 8      // rows per wave
#define NT 1024

typedef float v2f __attribute__((ext_vector_type(2)));

__device__ __forceinline__ float dpp_shr1(float old_v, float src) {
    // lane l gets lane l-1's src; lane 0 (invalid) keeps old_v (= left clamp)
    return __int_as_float(__builtin_amdgcn_update_dpp(
        __float_as_int(old_v), __float_as_int(src), 0x138, 0xf, 0xf, false));
}
__device__ __forceinline__ float dpp_shl1(float old_v, float src) {
    // lane l gets lane l+1's src; lane 63 (invalid) keeps old_v (= right clamp)
    return __int_as_float(__builtin_amdgcn_update_dpp(
        __float_as_int(old_v), __float_as_int(src), 0x130, 0xf, 0xf, false));
}

// d = a * b.yx   (packed f32 mul; half-swap on src1 via op_sel, no mov needed)
__device__ __forceinline__ v2f pk_mul_yx(v2f a, v2f b) {
    v2f d;
    asm("v_pk_mul_f32 %0, %1, %2 op_sel:[0,1] op_sel_hi:[1,0]"
        : "=v"(d) : "v"(a), "v"(b));
    return d;
}
// d = a * b + c  (packed f32 fma)
__device__ __forceinline__ v2f pk_fma(v2f a, v2f b, v2f c) {
    v2f d;
    asm("v_pk_fma_f32 %0, %1, %2, %3 op_sel:[0,0,0] op_sel_hi:[1,1,1]"
        : "=v"(d) : "v"(a), "v"(b), "v"(c));
    return d;
}

__global__ void __launch_bounds__(NT, 4)
jacobi_flux_kernel(const float* __restrict__ k_all,
                   const int* __restrict__ iters_p,
                   float* __restrict__ out)
{
    __shared__ __align__(16) v2f sTop[2][NW][64];   // 16 KB
    __shared__ __align__(16) v2f sBot[2][NW][64];   // 16 KB

    const int b   = blockIdx.x;
    const int tid = threadIdx.x;
    const int l   = tid & 63;           // lane
    const int w   = tid >> 6;           // wave 0..15
    const int R0  = w * RPW;            // first grid row of my strip
    const int c0  = l * 2;              // first grid col of my pair
    const float* kb = k_all + b * GH * GW;
    const int iters = *iters_p;

    const int wUp = (w == 0)      ? 0      : w - 1;
    const int wDn = (w == NW - 1) ? NW - 1 : w + 1;
    const bool gTop = (w == 0);
    const bool gBot = (w == NW - 1);

    // ---- one-time: normalized face conductivities, packed for the
    //      regrouped stencil: rN, rS (vertical), cM=(cE.x,cW.y), cLR=(cW.x,cE.y)
    v2f rN[RPW], rS[RPW], cM[RPW], cLR[RPW];
    #pragma unroll
    for (int i = 0; i < RPW; ++i) {
        const int r  = R0 + i;
        const int ru = (r == 0)      ? 0      : r - 1;
        const int rd = (r == GH - 1) ? GH - 1 : r + 1;
        float v[2][4];
        #pragma unroll
        for (int jj = 0; jj < 2; ++jj) {
            const int c  = c0 + jj;
            const int cl = (c == 0)      ? 0      : c - 1;
            const int cr = (c == GW - 1) ? GW - 1 : c + 1;
            float kc = kb[r * GW + c];
            float kn = 0.5f * (kc + kb[ru * GW + c]);
            float ks = 0.5f * (kc + kb[rd * GW + c]);
            float kw = 0.5f * (kc + kb[r * GW + cl]);
            float ke = 0.5f * (kc + kb[r * GW + cr]);
            float inv = 1.0f / (kn + ks + kw + ke);
            v[jj][0] = kn * inv; v[jj][1] = ks * inv;
            v[jj][2] = kw * inv; v[jj][3] = ke * inv;
        }
        rN[i]  = (v2f){v[0][0], v[1][0]};
        rS[i]  = (v2f){v[0][1], v[1][1]};
        cM[i]  = (v2f){v[0][3], v[1][2]};   // (cE.x, cW.y) pairs with cc.yx
        cLR[i] = (v2f){v[0][2], v[1][3]};   // (cW.x, cE.y) pairs with (lfv,rtv)
    }

    // ---- state ----
    v2f A[RPW], B[RPW];
    #pragma unroll
    for (int i = 0; i < RPW; ++i)
        A[i] = (R0 + i == 0) ? (v2f){1.0f, 1.0f} : (v2f){0.0f, 0.0f};

    sTop[0][w][l] = A[0];
    sBot[0][w][l] = A[RPW - 1];
    __syncthreads();

    auto step = [&](const v2f (&src)[RPW], v2f (&dst)[RPW], int rp, int wp) {
        // vertical halos (issued first; latency hides under DPP + pk chain)
        v2f hu = sBot[rp][wUp][l];   // grid row R0-1
        v2f hd = sTop[rp][wDn][l];   // grid row R0+RPW

        #pragma unroll
        for (int i = 0; i < RPW; ++i) {
            v2f cc = src[i];
            // (lfv, rtv): two DPP results, used only as a packed pair
            v2f s;
            s.x = dpp_shr1(cc.x, cc.y);   // left  neighbor (clamped at col 0)
            s.y = dpp_shl1(cc.y, cc.x);   // right neighbor (clamped at col 127)
            v2f up = (i == 0)       ? hu : src[i - 1];
            v2f dn = (i == RPW - 1) ? hd : src[i + 1];
            // dst = rN*up + rS*dn + cLR*(lfv,rtv) + cM*cc.yx  (all VOP3P)
            dst[i] = pk_fma(rN[i], up,
                     pk_fma(rS[i], dn,
                     pk_fma(cLR[i], s, pk_mul_yx(cM[i], cc))));
        }
        if (gTop) dst[0]       = (v2f){1.0f, 1.0f};   // Dirichlet row 0
        if (gBot) dst[RPW - 1] = (v2f){0.0f, 0.0f};   // Dirichlet row 127

        sTop[wp][w][l] = dst[0];
        sBot[wp][w][l] = dst[RPW - 1];
        __syncthreads();
    };

    const int nPairs = iters >> 1;
    for (int it = 0; it < nPairs; ++it) {
        step(A, B, 0, 1);
        step(B, A, 1, 0);
    }
    if (iters & 1) {
        step(A, B, 0, 1);
        #pragma unroll
        for (int i = 0; i < RPW; ++i) A[i] = B[i];
    }

    // ---- flux at row 64: wave 8 holds rows 64..71 (A[0]=r64, A[1]=r65) ----
    if (w == 8) {
        float partial = kb[64 * GW + c0]     * (A[1].x - A[0].x)
                      + kb[64 * GW + c0 + 1] * (A[1].y - A[0].y);
        #pragma unroll
        for (int off = 32; off > 0; off >>= 1)
            partial += __shfl_down(partial, off, 64);
        if (l == 0) out[b] = -partial;
    }
}

extern "C" void kernel_launch(void* const* d_in, const int* in_sizes, int n_in,
                              void* d_out, int out_size, void* d_ws, size_t ws_size,
                              hipStream_t stream)
{
    const float* k     = (const float*)d_in[0];
    const int*   iters = (const int*)d_in[1];
    float*       out   = (float*)d_out;
    jacobi_flux_kernel<<<dim3(8), dim3(NT), 0, stream>>>(k, iters, out);
}

// Round 2
// 589.417 us; speedup vs baseline: 1.0179x; 1.0179x over previous
//
#include <hip/hip_runtime.h>

// Batched Jacobi diffusion, B=8, 128x128, iters=1000. One 1024-thread block
// per batch. Wave-strip layout: 16 waves x 8 grid rows; lane owns a float2
// column pair. VALU-issue-bound on 8 active CUs (VALUBusy ~80% there).
//
// Round 15: pin occupancy with amdgpu_waves_per_eu(4,4).
// Evidence from r13/r14: VGPR_Count 64/60 with ~132 VALU instr/wave/step
// (ideal is ~70), no scratch traffic in FETCH_SIZE -> the 64-reg coefficient
// set lives in AGPRs and every step pays ~64 v_accvgpr_read ops. The
// allocator maximizes occupancy within [min,inf) and (gfx908-lineage cost
// model) treats AGPRs as free for occupancy -- wrong on gfx950's unified
// VGPR/AGPR file, where 60 arch + 64 agpr = 124 total still only fits
// 4 waves/EU. Pinning waves_per_eu to exactly [4,4] gives the allocator a
// 128-reg arch budget and no reason to spill: coefficient + state set
// (~124 regs) fits in arch VGPRs, killing the churn.
// Target per row: 2 mov + 2 DPP + 1 pk_mul + 3 pk_fma = 8 VALU slots.

#define GH 128
#define GW 128
#define NW 16      // waves per block
#define RPW 8      // rows per wave
#define NT 1024

typedef float v2f __attribute__((ext_vector_type(2)));

__device__ __forceinline__ float dpp_shr1(float old_v, float src) {
    // lane l gets lane l-1's src; lane 0 (invalid) keeps old_v (= left clamp)
    return __int_as_float(__builtin_amdgcn_update_dpp(
        __float_as_int(old_v), __float_as_int(src), 0x138, 0xf, 0xf, false));
}
__device__ __forceinline__ float dpp_shl1(float old_v, float src) {
    // lane l gets lane l+1's src; lane 63 (invalid) keeps old_v (= right clamp)
    return __int_as_float(__builtin_amdgcn_update_dpp(
        __float_as_int(old_v), __float_as_int(src), 0x130, 0xf, 0xf, false));
}

// d = a * b.yx   (packed f32 mul; half-swap on src1 via op_sel, no mov needed)
__device__ __forceinline__ v2f pk_mul_yx(v2f a, v2f b) {
    v2f d;
    asm("v_pk_mul_f32 %0, %1, %2 op_sel:[0,1] op_sel_hi:[1,0]"
        : "=v"(d) : "v"(a), "v"(b));
    return d;
}
// d = a * b + c  (packed f32 fma)
__device__ __forceinline__ v2f pk_fma(v2f a, v2f b, v2f c) {
    v2f d;
    asm("v_pk_fma_f32 %0, %1, %2, %3 op_sel:[0,0,0] op_sel_hi:[1,1,1]"
        : "=v"(d) : "v"(a), "v"(b), "v"(c));
    return d;
}

__global__ void __launch_bounds__(NT)
__attribute__((amdgpu_waves_per_eu(4, 4)))
jacobi_flux_kernel(const float* __restrict__ k_all,
                   const int* __restrict__ iters_p,
                   float* __restrict__ out)
{
    __shared__ __align__(16) v2f sTop[2][NW][64];   // 16 KB
    __shared__ __align__(16) v2f sBot[2][NW][64];   // 16 KB

    const int b   = blockIdx.x;
    const int tid = threadIdx.x;
    const int l   = tid & 63;           // lane
    const int w   = tid >> 6;           // wave 0..15
    const int R0  = w * RPW;            // first grid row of my strip
    const int c0  = l * 2;              // first grid col of my pair
    const float* kb = k_all + b * GH * GW;
    const int iters = *iters_p;

    const int wUp = (w == 0)      ? 0      : w - 1;
    const int wDn = (w == NW - 1) ? NW - 1 : w + 1;
    const bool gTop = (w == 0);
    const bool gBot = (w == NW - 1);

    // ---- one-time: normalized face conductivities, packed for the
    //      regrouped stencil: rN, rS (vertical), cM=(cE.x,cW.y), cLR=(cW.x,cE.y)
    v2f rN[RPW], rS[RPW], cM[RPW], cLR[RPW];
    #pragma unroll
    for (int i = 0; i < RPW; ++i) {
        const int r  = R0 + i;
        const int ru = (r == 0)      ? 0      : r - 1;
        const int rd = (r == GH - 1) ? GH - 1 : r + 1;
        float v[2][4];
        #pragma unroll
        for (int jj = 0; jj < 2; ++jj) {
            const int c  = c0 + jj;
            const int cl = (c == 0)      ? 0      : c - 1;
            const int cr = (c == GW - 1) ? GW - 1 : c + 1;
            float kc = kb[r * GW + c];
            float kn = 0.5f * (kc + kb[ru * GW + c]);
            float ks = 0.5f * (kc + kb[rd * GW + c]);
            float kw = 0.5f * (kc + kb[r * GW + cl]);
            float ke = 0.5f * (kc + kb[r * GW + cr]);
            float inv = 1.0f / (kn + ks + kw + ke);
            v[jj][0] = kn * inv; v[jj][1] = ks * inv;
            v[jj][2] = kw * inv; v[jj][3] = ke * inv;
        }
        rN[i]  = (v2f){v[0][0], v[1][0]};
        rS[i]  = (v2f){v[0][1], v[1][1]};
        cM[i]  = (v2f){v[0][3], v[1][2]};   // (cE.x, cW.y) pairs with cc.yx
        cLR[i] = (v2f){v[0][2], v[1][3]};   // (cW.x, cE.y) pairs with (lfv,rtv)
    }

    // ---- state ----
    v2f A[RPW], B[RPW];
    #pragma unroll
    for (int i = 0; i < RPW; ++i)
        A[i] = (R0 + i == 0) ? (v2f){1.0f, 1.0f} : (v2f){0.0f, 0.0f};

    sTop[0][w][l] = A[0];
    sBot[0][w][l] = A[RPW - 1];
    __syncthreads();

    auto step = [&](const v2f (&src)[RPW], v2f (&dst)[RPW], int rp, int wp) {
        // vertical halos (issued first; latency hides under DPP + pk chain)
        v2f hu = sBot[rp][wUp][l];   // grid row R0-1
        v2f hd = sTop[rp][wDn][l];   // grid row R0+RPW

        #pragma unroll
        for (int i = 0; i < RPW; ++i) {
            v2f cc = src[i];
            // (lfv, rtv): two DPP results, used only as a packed pair
            v2f s;
            s.x = dpp_shr1(cc.x, cc.y);   // left  neighbor (clamped at col 0)
            s.y = dpp_shl1(cc.y, cc.x);   // right neighbor (clamped at col 127)
            v2f up = (i == 0)       ? hu : src[i - 1];
            v2f dn = (i == RPW - 1) ? hd : src[i + 1];
            // dst = rN*up + rS*dn + cLR*(lfv,rtv) + cM*cc.yx  (all VOP3P)
            dst[i] = pk_fma(rN[i], up,
                     pk_fma(rS[i], dn,
                     pk_fma(cLR[i], s, pk_mul_yx(cM[i], cc))));
        }
        if (gTop) dst[0]       = (v2f){1.0f, 1.0f};   // Dirichlet row 0
        if (gBot) dst[RPW - 1] = (v2f){0.0f, 0.0f};   // Dirichlet row 127

        sTop[wp][w][l] = dst[0];
        sBot[wp][w][l] = dst[RPW - 1];
        __syncthreads();
    };

    const int nPairs = iters >> 1;
    for (int it = 0; it < nPairs; ++it) {
        step(A, B, 0, 1);
        step(B, A, 1, 0);
    }
    if (iters & 1) {
        step(A, B, 0, 1);
        #pragma unroll
        for (int i = 0; i < RPW; ++i) A[i] = B[i];
    }

    // ---- flux at row 64: wave 8 holds rows 64..71 (A[0]=r64, A[1]=r65) ----
    if (w == 8) {
        float partial = kb[64 * GW + c0]     * (A[1].x - A[0].x)
                      + kb[64 * GW + c0 + 1] * (A[1].y - A[0].y);
        #pragma unroll
        for (int off = 32; off > 0; off >>= 1)
            partial += __shfl_down(partial, off, 64);
        if (l == 0) out[b] = -partial;
    }
}

extern "C" void kernel_launch(void* const* d_in, const int* in_sizes, int n_in,
                              void* d_out, int out_size, void* d_ws, size_t ws_size,
                              hipStream_t stream)
{
    const float* k     = (const float*)d_in[0];
    const int*   iters = (const int*)d_in[1];
    float*       out   = (float*)d_out;
    jacobi_flux_kernel<<<dim3(8), dim3(NT), 0, stream>>>(k, iters, out);
}